// Round 1
// baseline (443.129 us; speedup 1.0000x reference)
//
#include <hip/hip_runtime.h>

#define TSTEPS 256
#define CHUNK  64   // t-steps per block; halo = 8 extra reads per chunk

__device__ __forceinline__ float4 f4mul(const float4 a, const float4 b) {
    return make_float4(a.x * b.x, a.y * b.y, a.z * b.z, a.w * b.w);
}
// 1 - a*b*m  (elementwise over a,m; b scalar) — the "NAND with delayed n1" stage
__device__ __forceinline__ float4 f4nandm(const float4 a, const float b, const float4 m) {
    return make_float4(1.f - a.x * b * m.x, 1.f - a.y * b * m.y,
                       1.f - a.z * b * m.z, 1.f - a.w * b * m.w);
}

__global__ __launch_bounds__(256) void tanhP1_kernel(
    const float* __restrict__ x,
    const float* __restrict__ c2, const float* __restrict__ c3,
    const float* __restrict__ c4, const float* __restrict__ c5,
    float* __restrict__ out, int N4)
{
    __shared__ float sb2[TSTEPS], sb3[TSTEPS], sb4[TSTEPS], sb5[TSTEPS];
    const int tid = threadIdx.x;
    if (tid < TSTEPS) {            // block=256 → one element per thread
        sb2[tid] = c2[tid]; sb3[tid] = c3[tid];
        sb4[tid] = c4[tid]; sb5[tid] = c5[tid];
    }
    __syncthreads();

    const int j4 = blockIdx.x * blockDim.x + tid;   // float4 column index
    if (j4 >= N4) return;
    const int t0 = blockIdx.y * CHUNK;

    const float4* __restrict__ x4   = (const float4*)x;
    float4* __restrict__       out4 = (float4*)out;

    float4 xd[8];  // xd[k] = x[t-1-k]  (shift register of delayed inputs)
    float4 m[3];   // m[k]  = n1[t-1-k]

    if (t0 == 0) {
        // matches the reference's zero-initialized carry
        #pragma unroll
        for (int k = 0; k < 8; ++k) xd[k] = make_float4(0.f, 0.f, 0.f, 0.f);
        #pragma unroll
        for (int k = 0; k < 3; ++k) m[k] = make_float4(0.f, 0.f, 0.f, 0.f);
    } else {
        // halo preload: t0 >= 64, so t0-8 >= 0 — all loads in range
        #pragma unroll
        for (int k = 0; k < 8; ++k)
            xd[k] = x4[(size_t)(t0 - 1 - k) * N4 + j4];
        // n1[t0-1-k] = x[t0-1-k] * x[t0-5-k] = xd[k] * xd[k+4]
        #pragma unroll
        for (int k = 0; k < 3; ++k)
            m[k] = f4mul(xd[k], xd[k + 4]);
    }

    #pragma unroll 8
    for (int t = t0; t < t0 + CHUNK; ++t) {
        const float4 xt = x4[(size_t)t * N4 + j4];
        const float b2 = sb2[t], b3 = sb3[t], b4 = sb4[t], b5 = sb5[t];

        const float4 n1 = f4mul(xt, xd[3]);                       // x[t] & x[t-4]
        const float4 n2 = make_float4(1.f - n1.x * b2, 1.f - n1.y * b2,
                                      1.f - n1.z * b2, 1.f - n1.w * b2);
        const float4 n3 = f4nandm(n2, b3, m[0]);
        const float4 n4 = f4nandm(n3, b4, m[1]);
        const float4 n5 = f4nandm(n4, b5, m[2]);

        out4[(size_t)t * N4 + j4] = f4mul(n5, xd[7]);             // n5 & x[t-8]

        // shift delay lines (register renames after unroll)
        xd[7] = xd[6]; xd[6] = xd[5]; xd[5] = xd[4]; xd[4] = xd[3];
        xd[3] = xd[2]; xd[2] = xd[1]; xd[1] = xd[0]; xd[0] = xt;
        m[2] = m[1]; m[1] = m[0]; m[0] = n1;
    }
}

extern "C" void kernel_launch(void* const* d_in, const int* in_sizes, int n_in,
                              void* d_out, int out_size, void* d_ws, size_t ws_size,
                              hipStream_t stream) {
    const float* x  = (const float*)d_in[0];
    const float* c2 = (const float*)d_in[1];
    const float* c3 = (const float*)d_in[2];
    const float* c4 = (const float*)d_in[3];
    const float* c5 = (const float*)d_in[4];
    float* out = (float*)d_out;

    const int N  = in_sizes[0] / TSTEPS;  // 262144
    const int N4 = N / 4;                 // 65536 float4 columns

    dim3 block(256);
    dim3 grid((N4 + 255) / 256, TSTEPS / CHUNK);  // 256 x 4 = 1024 blocks
    tanhP1_kernel<<<grid, block, 0, stream>>>(x, c2, c3, c4, c5, out, N4);
}